// Round 1
// baseline (1040.559 us; speedup 1.0000x reference)
//
#include <hip/hip_runtime.h>

#define NB 4
#define NN 65536
#define NK 16
#define NP (NB * NN)   // 262144 points
#define BN_EPS 1e-6f

// ---- workspace layout (floats) ----
// raw sums (zeroed each launch): contiguous so one blockReduceAtomic covers them
#define WS_S_Y1    0    // 8   lse1 conv sum
#define WS_SS_Y1   8    // 8   lse1 conv sumsq
#define WS_S_Y3    16   // 8   lse2 conv sum
#define WS_SS_Y3   24   // 8   lse2 conv sumsq
#define WS_S_SC    32   // 32  shortcut conv sum
#define WS_SS_SC   64   // 32  shortcut conv sumsq
#define WS_S_Y2    96   // 8   pool1 conv sum
#define WS_SS_Y2   104  // 8
#define WS_S_Y4    112  // 16  pool2 conv sum
#define WS_SS_Y4   128  // 16  -> 144 floats total raw stats
// finalized scale/shift (bn(x) = x*scale + shift)
#define WS_BN1_SC  160
#define WS_BN1_SH  168
#define WS_BN3_SC  176
#define WS_BN3_SH  184
#define WS_BNSC_SC 192  // 32
#define WS_BNSC_SH 224  // 32
#define WS_BNP1_SC 256
#define WS_BNP1_SH 264
#define WS_BNP2_SC 272  // 16
#define WS_BNP2_SH 288  // ..304
// big buffers, channel-major [c][p] for coalesced access
#define WS_Y2      1024             // NP*8  floats (8 MB)
#define WS_Y4      (1024 + NP * 8)  // NP*16 floats (16 MB)

template <int NCH>
__device__ inline void blockReduceAtomic(float (&v)[NCH], float* __restrict__ dst) {
    __shared__ float red[4][NCH];  // blockDim.x == 256 -> 4 waves
    const int lane = threadIdx.x & 63;
    const int wv = threadIdx.x >> 6;
#pragma unroll
    for (int c = 0; c < NCH; c++) {
        float x = v[c];
#pragma unroll
        for (int off = 32; off > 0; off >>= 1) x += __shfl_xor(x, off, 64);
        if (lane == 0) red[wv][c] = x;
    }
    __syncthreads();
    for (int c = threadIdx.x; c < NCH; c += 256)
        atomicAdd(dst + c, red[0][c] + red[1][c] + red[2][c] + red[3][c]);
}

// ---------------- Kernel 1: stats for bn(lse1 conv), bn(lse2 conv), bn(shortcut conv)
__global__ __launch_bounds__(256) void k_stats1(
    const float* __restrict__ coords, const float* __restrict__ feats,
    const int* __restrict__ idx,
    const float* __restrict__ lse1_w, const float* __restrict__ lse1_b,
    const float* __restrict__ lse2_w, const float* __restrict__ lse2_b,
    const float* __restrict__ sc_w, const float* __restrict__ sc_b,
    float* __restrict__ ws) {
    __shared__ float w1s[80], b1s[8], w3s[80], b3s[8], wscs[256], bscs[32];
    const int tid = threadIdx.x;
    for (int i = tid; i < 80; i += 256) { w1s[i] = lse1_w[i]; w3s[i] = lse2_w[i]; }
    if (tid < 8) { b1s[tid] = lse1_b[tid]; b3s[tid] = lse2_b[tid]; }
    if (tid < 256) wscs[tid] = sc_w[tid];
    if (tid < 32) bscs[tid] = sc_b[tid];
    __syncthreads();

    // acc layout matches ws[0..96): [s_y1 ss_y1 s_y3 ss_y3 s_sc(32) ss_sc(32)]
    float acc[96] = {};

    for (int p = blockIdx.x * 256 + tid; p < NP; p += gridDim.x * 256) {
        const int b = p >> 16;
        const int n = p & (NN - 1);
        const float cx = coords[3 * p], cy = coords[3 * p + 1], cz = coords[3 * p + 2];
        const float* cb = coords + b * NN * 3;
        const int4* ip = (const int4*)idx + p * 4;
        int nb[16];
#pragma unroll
        for (int q = 0; q < 4; q++) {
            int4 v = ip[q];
            nb[4 * q] = v.x; nb[4 * q + 1] = v.y; nb[4 * q + 2] = v.z; nb[4 * q + 3] = v.w;
        }
#pragma unroll
        for (int k = 0; k < 16; k++) {
            const int j = nb[k];
            const float nx = cb[3 * j], ny = cb[3 * j + 1], nz = cb[3 * j + 2];
            const float e6 = cx - nx, e7 = cy - ny, e8 = cz - nz;
#pragma unroll
            for (int c = 0; c < 8; c++) {
                const float* w = &w1s[c * 10];
                float y = b1s[c] + w[9] + cx * w[0] + cy * w[1] + cz * w[2] +
                          nx * w[3] + ny * w[4] + nz * w[5] + e6 * w[6] + e7 * w[7] + e8 * w[8];
                acc[c] += y; acc[8 + c] += y * y;
                const float* v = &w3s[c * 10];
                float z = b3s[c] + v[9] + cx * v[0] + cy * v[1] + cz * v[2] +
                          nx * v[3] + ny * v[4] + nz * v[5] + e6 * v[6] + e7 * v[7] + e8 * v[8];
                acc[16 + c] += z; acc[24 + c] += z * z;
            }
        }
        float f[8];
#pragma unroll
        for (int i = 0; i < 8; i++) f[i] = feats[(b * 8 + i) * NN + n];
#pragma unroll
        for (int c = 0; c < 32; c++) {
            const float* w = &wscs[c * 8];
            float y = bscs[c];
#pragma unroll
            for (int i = 0; i < 8; i++) y += f[i] * w[i];
            acc[32 + c] += y; acc[64 + c] += y * y;
        }
    }
    blockReduceAtomic<96>(acc, ws);
}

// ---------------- finalize bn1 (count NP*NK), bn3 (NP*NK), bn_sc (NP)
__global__ void k_fin1(const float* __restrict__ g1, const float* __restrict__ bt1,
                       const float* __restrict__ g3, const float* __restrict__ bt3,
                       const float* __restrict__ gsc, const float* __restrict__ btsc,
                       float* __restrict__ ws) {
    const int t = threadIdx.x;
    const float cK = 1.f / (float)(NP * NK);
    const float cP = 1.f / (float)NP;
    if (t < 8) {
        float m = ws[WS_S_Y1 + t] * cK, v = ws[WS_SS_Y1 + t] * cK - m * m;
        float sc = g1[t] * rsqrtf(v + BN_EPS);
        ws[WS_BN1_SC + t] = sc; ws[WS_BN1_SH + t] = bt1[t] - m * sc;
    } else if (t < 16) {
        int c = t - 8;
        float m = ws[WS_S_Y3 + c] * cK, v = ws[WS_SS_Y3 + c] * cK - m * m;
        float sc = g3[c] * rsqrtf(v + BN_EPS);
        ws[WS_BN3_SC + c] = sc; ws[WS_BN3_SH + c] = bt3[c] - m * sc;
    } else if (t < 48) {
        int c = t - 16;
        float m = ws[WS_S_SC + c] * cP, v = ws[WS_SS_SC + c] * cP - m * m;
        float sc = gsc[c] * rsqrtf(v + BN_EPS);
        ws[WS_BNSC_SC + c] = sc; ws[WS_BNSC_SH + c] = btsc[c] - m * sc;
    }
}

// ---------------- Kernel 3: mlp1 + lse1 + pool1 -> y2 (pre-BN), bn_p1 stats
__global__ __launch_bounds__(256) void k_pool1(
    const float* __restrict__ coords, const float* __restrict__ feats,
    const int* __restrict__ idx,
    const float* __restrict__ w1, const float* __restrict__ b1,
    const float* __restrict__ lse1_w, const float* __restrict__ lse1_b,
    const float* __restrict__ p1_sw, const float* __restrict__ p1_w,
    const float* __restrict__ p1_b, float* __restrict__ ws) {
    __shared__ float lws[80], lbs[8], w1s[64], b1s[8], bnsc[8], bnsh[8],
        sws[64], pws[128], pbs[8];
    const int tid = threadIdx.x;
    for (int i = tid; i < 80; i += 256) lws[i] = lse1_w[i];
    if (tid < 8) {
        lbs[tid] = lse1_b[tid]; b1s[tid] = b1[tid]; pbs[tid] = p1_b[tid];
        bnsc[tid] = ws[WS_BN1_SC + tid]; bnsh[tid] = ws[WS_BN1_SH + tid];
    }
    if (tid < 64) {
        w1s[tid] = w1[tid];
        int o = tid >> 3, i2 = tid & 7;
        sws[tid] = p1_sw[o * 16 + i2];  // only rows o<8, cols i<8 matter
    }
    if (tid < 128) pws[tid] = p1_w[tid];
    __syncthreads();

    float st[16] = {};
    const int p = blockIdx.x * 256 + tid;
    if (p < NP) {
        const int b = p >> 16;
        const int n = p & (NN - 1);
        float f[8];
#pragma unroll
        for (int i = 0; i < 8; i++) f[i] = feats[(b * 8 + i) * NN + n];
        float x1[8];
#pragma unroll
        for (int j = 0; j < 8; j++) {
            float y = b1s[j];
#pragma unroll
            for (int i = 0; i < 8; i++) y += f[i] * w1s[j * 8 + i];
            x1[j] = y > 0.f ? y : 0.2f * y;  // LeakyReLU(0.2)
        }
        const float cx = coords[3 * p], cy = coords[3 * p + 1], cz = coords[3 * p + 2];
        const float* cb = coords + b * NN * 3;
        const int4* ip = (const int4*)idx + p * 4;
        int nb[16];
#pragma unroll
        for (int q = 0; q < 4; q++) {
            int4 v = ip[q];
            nb[4 * q] = v.x; nb[4 * q + 1] = v.y; nb[4 * q + 2] = v.z; nb[4 * q + 3] = v.w;
        }
        float l[8] = {}, ac[8] = {};
#pragma unroll
        for (int k = 0; k < 16; k++) {
            const int j = nb[k];
            const float nx = cb[3 * j], ny = cb[3 * j + 1], nz = cb[3 * j + 2];
            const float e6 = cx - nx, e7 = cy - ny, e8 = cz - nz;
            float h[8];
#pragma unroll
            for (int c = 0; c < 8; c++) {
                const float* w = &lws[c * 10];
                float y = lbs[c] + w[9] + cx * w[0] + cy * w[1] + cz * w[2] +
                          nx * w[3] + ny * w[4] + nz * w[5] + e6 * w[6] + e7 * w[7] + e8 * w[8];
                y = y * bnsc[c] + bnsh[c];
                h[c] = y > 0.f ? y : 0.f;
            }
#pragma unroll
            for (int o = 0; o < 8; o++) {
                float s = 0.f;
#pragma unroll
                for (int i = 0; i < 8; i++) s += h[i] * sws[o * 8 + i];
                // k-constant part of score cancels in softmax; |s| small -> no max needed
                float e = __expf(s);
                l[o] += e; ac[o] += e * h[o];
            }
        }
        float agg[16];
#pragma unroll
        for (int o = 0; o < 8; o++) agg[o] = ac[o] / l[o];
#pragma unroll
        for (int o = 0; o < 8; o++) agg[8 + o] = x1[o];  // softmax sums to 1
#pragma unroll
        for (int c = 0; c < 8; c++) {
            float y = pbs[c];
#pragma unroll
            for (int o = 0; o < 16; o++) y += agg[o] * pws[c * 16 + o];
            ws[WS_Y2 + c * NP + p] = y;
            st[c] = y; st[8 + c] = y * y;
        }
    }
    blockReduceAtomic<16>(st, ws + WS_S_Y2);
}

// ---------------- finalize bn_p1 (count NP)
__global__ void k_fin2(const float* __restrict__ g, const float* __restrict__ bt,
                       float* __restrict__ ws) {
    const int t = threadIdx.x;
    if (t < 8) {
        const float cP = 1.f / (float)NP;
        float m = ws[WS_S_Y2 + t] * cP, v = ws[WS_SS_Y2 + t] * cP - m * m;
        float sc = g[t] * rsqrtf(v + BN_EPS);
        ws[WS_BNP1_SC + t] = sc; ws[WS_BNP1_SH + t] = bt[t] - m * sc;
    }
}

// ---------------- Kernel 5: bn_p1+relu -> x2, lse2 + pool2 -> y4 (pre-BN), bn_p2 stats
__global__ __launch_bounds__(256) void k_pool2(
    const float* __restrict__ coords, const int* __restrict__ idx,
    const float* __restrict__ lse2_w, const float* __restrict__ lse2_b,
    const float* __restrict__ p2_sw, const float* __restrict__ p2_w,
    const float* __restrict__ p2_b, float* __restrict__ ws) {
    __shared__ float lws[80], lbs[8], bnsc[8], bnsh[8], p1sc[8], p1sh[8],
        sws[64], pws[256], pbs[16];
    const int tid = threadIdx.x;
    for (int i = tid; i < 80; i += 256) lws[i] = lse2_w[i];
    if (tid < 8) {
        lbs[tid] = lse2_b[tid];
        bnsc[tid] = ws[WS_BN3_SC + tid]; bnsh[tid] = ws[WS_BN3_SH + tid];
        p1sc[tid] = ws[WS_BNP1_SC + tid]; p1sh[tid] = ws[WS_BNP1_SH + tid];
    }
    if (tid < 64) {
        int o = tid >> 3, i2 = tid & 7;
        sws[tid] = p2_sw[o * 16 + i2];
    }
    if (tid < 256) pws[tid] = p2_w[tid];
    if (tid < 16) pbs[tid] = p2_b[tid];
    __syncthreads();

    float st[32] = {};
    const int p = blockIdx.x * 256 + tid;
    if (p < NP) {
        const int b = p >> 16;
        float x2[8];
#pragma unroll
        for (int c = 0; c < 8; c++) {
            float y = ws[WS_Y2 + c * NP + p] * p1sc[c] + p1sh[c];
            x2[c] = y > 0.f ? y : 0.f;
        }
        const float cx = coords[3 * p], cy = coords[3 * p + 1], cz = coords[3 * p + 2];
        const float* cb = coords + b * NN * 3;
        const int4* ip = (const int4*)idx + p * 4;
        int nb[16];
#pragma unroll
        for (int q = 0; q < 4; q++) {
            int4 v = ip[q];
            nb[4 * q] = v.x; nb[4 * q + 1] = v.y; nb[4 * q + 2] = v.z; nb[4 * q + 3] = v.w;
        }
        float l[8] = {}, ac[8] = {};
#pragma unroll
        for (int k = 0; k < 16; k++) {
            const int j = nb[k];
            const float nx = cb[3 * j], ny = cb[3 * j + 1], nz = cb[3 * j + 2];
            const float e6 = cx - nx, e7 = cy - ny, e8 = cz - nz;
            float h[8];
#pragma unroll
            for (int c = 0; c < 8; c++) {
                const float* w = &lws[c * 10];
                float y = lbs[c] + w[9] + cx * w[0] + cy * w[1] + cz * w[2] +
                          nx * w[3] + ny * w[4] + nz * w[5] + e6 * w[6] + e7 * w[7] + e8 * w[8];
                y = y * bnsc[c] + bnsh[c];
                h[c] = y > 0.f ? y : 0.f;
            }
#pragma unroll
            for (int o = 0; o < 8; o++) {
                float s = 0.f;
#pragma unroll
                for (int i = 0; i < 8; i++) s += h[i] * sws[o * 8 + i];
                float e = __expf(s);
                l[o] += e; ac[o] += e * h[o];
            }
        }
        float agg[16];
#pragma unroll
        for (int o = 0; o < 8; o++) agg[o] = ac[o] / l[o];
#pragma unroll
        for (int o = 0; o < 8; o++) agg[8 + o] = x2[o];
#pragma unroll
        for (int c = 0; c < 16; c++) {
            float y = pbs[c];
#pragma unroll
            for (int o = 0; o < 16; o++) y += agg[o] * pws[c * 16 + o];
            ws[WS_Y4 + c * NP + p] = y;
            st[c] = y; st[16 + c] = y * y;
        }
    }
    blockReduceAtomic<32>(st, ws + WS_S_Y4);
}

// ---------------- finalize bn_p2 (count NP)
__global__ void k_fin3(const float* __restrict__ g, const float* __restrict__ bt,
                       float* __restrict__ ws) {
    const int t = threadIdx.x;
    if (t < 16) {
        const float cP = 1.f / (float)NP;
        float m = ws[WS_S_Y4 + t] * cP, v = ws[WS_SS_Y4 + t] * cP - m * m;
        float sc = g[t] * rsqrtf(v + BN_EPS);
        ws[WS_BNP2_SC + t] = sc; ws[WS_BNP2_SH + t] = bt[t] - m * sc;
    }
}

// ---------------- Kernel 7: x4 = relu(bn(y4)); out = leaky(w2@x4 + b2 + bn(sc_w@feats))
__global__ __launch_bounds__(256) void k_final(
    const float* __restrict__ feats, const float* __restrict__ w2,
    const float* __restrict__ b2, const float* __restrict__ sc_w,
    const float* __restrict__ sc_b, const float* __restrict__ ws,
    float* __restrict__ out) {
    __shared__ float w2s[512], b2s[32], scws[256], scbs[32],
        p2sc[16], p2sh[16], scsc[32], scsh[32];
    const int tid = threadIdx.x;
    for (int i = tid; i < 512; i += 256) w2s[i] = w2[i];
    if (tid < 256) scws[tid] = sc_w[tid];
    if (tid < 32) {
        b2s[tid] = b2[tid]; scbs[tid] = sc_b[tid];
        scsc[tid] = ws[WS_BNSC_SC + tid]; scsh[tid] = ws[WS_BNSC_SH + tid];
    }
    if (tid < 16) { p2sc[tid] = ws[WS_BNP2_SC + tid]; p2sh[tid] = ws[WS_BNP2_SH + tid]; }
    __syncthreads();

    const int p = blockIdx.x * 256 + tid;
    if (p >= NP) return;
    const int b = p >> 16;
    const int n = p & (NN - 1);
    float x4[16];
#pragma unroll
    for (int c = 0; c < 16; c++) {
        float y = ws[WS_Y4 + c * NP + p] * p2sc[c] + p2sh[c];
        x4[c] = y > 0.f ? y : 0.f;
    }
    float f[8];
#pragma unroll
    for (int i = 0; i < 8; i++) f[i] = feats[(b * 8 + i) * NN + n];
#pragma unroll
    for (int c = 0; c < 32; c++) {
        float s = scbs[c];
#pragma unroll
        for (int i = 0; i < 8; i++) s += f[i] * scws[c * 8 + i];
        s = s * scsc[c] + scsh[c];  // bn, no activation
        float m = b2s[c];
#pragma unroll
        for (int o = 0; o < 16; o++) m += x4[o] * w2s[c * 16 + o];
        float v = m + s;
        out[(b * 32 + c) * NN + n] = v > 0.f ? v : 0.01f * v;  // LeakyReLU(0.01)
    }
}

extern "C" void kernel_launch(void* const* d_in, const int* in_sizes, int n_in,
                              void* d_out, int out_size, void* d_ws, size_t ws_size,
                              hipStream_t stream) {
    (void)in_sizes; (void)n_in; (void)out_size; (void)ws_size;
    const float* coords = (const float*)d_in[0];
    const float* features = (const float*)d_in[1];
    const int* idx = (const int*)d_in[2];
    const float* w1 = (const float*)d_in[3];
    const float* b1 = (const float*)d_in[4];
    const float* lse1_w = (const float*)d_in[5];
    const float* lse1_b = (const float*)d_in[6];
    const float* lse1_g = (const float*)d_in[7];
    const float* lse1_bt = (const float*)d_in[8];
    const float* p1_sw = (const float*)d_in[9];
    const float* p1_w = (const float*)d_in[10];
    const float* p1_b = (const float*)d_in[11];
    const float* p1_g = (const float*)d_in[12];
    const float* p1_bt = (const float*)d_in[13];
    const float* lse2_w = (const float*)d_in[14];
    const float* lse2_b = (const float*)d_in[15];
    const float* lse2_g = (const float*)d_in[16];
    const float* lse2_bt = (const float*)d_in[17];
    const float* p2_sw = (const float*)d_in[18];
    const float* p2_w = (const float*)d_in[19];
    const float* p2_b = (const float*)d_in[20];
    const float* p2_g = (const float*)d_in[21];
    const float* p2_bt = (const float*)d_in[22];
    const float* w2 = (const float*)d_in[23];
    const float* b2 = (const float*)d_in[24];
    const float* sc_w = (const float*)d_in[25];
    const float* sc_b = (const float*)d_in[26];
    const float* sc_g = (const float*)d_in[27];
    const float* sc_bt = (const float*)d_in[28];
    float* ws = (float*)d_ws;
    float* out = (float*)d_out;

    hipMemsetAsync(ws, 0, 144 * sizeof(float), stream);
    k_stats1<<<512, 256, 0, stream>>>(coords, features, idx, lse1_w, lse1_b,
                                      lse2_w, lse2_b, sc_w, sc_b, ws);
    k_fin1<<<1, 64, 0, stream>>>(lse1_g, lse1_bt, lse2_g, lse2_bt, sc_g, sc_bt, ws);
    k_pool1<<<NP / 256, 256, 0, stream>>>(coords, features, idx, w1, b1, lse1_w,
                                          lse1_b, p1_sw, p1_w, p1_b, ws);
    k_fin2<<<1, 64, 0, stream>>>(p1_g, p1_bt, ws);
    k_pool2<<<NP / 256, 256, 0, stream>>>(coords, idx, lse2_w, lse2_b, p2_sw,
                                          p2_w, p2_b, ws);
    k_fin3<<<1, 64, 0, stream>>>(p2_g, p2_bt, ws);
    k_final<<<NP / 256, 256, 0, stream>>>(features, w2, b2, sc_w, sc_b, ws, out);
}

// Round 2
// 352.926 us; speedup vs baseline: 2.9484x; 2.9484x over previous
//
#include <hip/hip_runtime.h>

#define NB 4
#define NN 65536
#define NK 16
#define NP (NB * NN)   // 262144 points
#define BN_EPS 1e-6f

// ---- workspace layout (floats) ----
// raw sums (zeroed each launch):
// enc moments over all (p,k), basis [cx,cy,cz,nx,ny,nz,1]:
//   [0..2]  S_c   (x16 per point)
//   [3..5]  S_n
//   [6..11] M_cc  (sym upper: 00,01,02,11,12,22; x16 per point)
//   [12..20] M_cn (full 3x3 row-major, = c_i * sum_k n_j)
//   [21..26] M_nn (sym upper)
#define WS_ENC_M   0    // 27 floats
// shortcut feature moments over points: S_f[8] @32, M_ff upper-tri 36 @40
#define WS_SC_M    32   // 44 floats
#define WS_S_Y2    96   // 8   pool1 conv sum
#define WS_SS_Y2   104  // 8
#define WS_S_Y4    112  // 16  pool2 conv sum
#define WS_SS_Y4   128  // 16  -> raw stats end at 144
// finalized scale/shift (bn(x) = x*scale + shift)
#define WS_BN1_SC  160
#define WS_BN1_SH  168
#define WS_BN3_SC  176
#define WS_BN3_SH  184
#define WS_BNSC_SC 192  // 32
#define WS_BNSC_SH 224  // 32
#define WS_BNP1_SC 256
#define WS_BNP1_SH 264
#define WS_BNP2_SC 272  // 16
#define WS_BNP2_SH 288  // ..304
// big buffers, channel-major [c][p] for coalesced access
#define WS_Y2      1024             // NP*8  floats (8 MB)
#define WS_Y4      (1024 + NP * 8)  // NP*16 floats (16 MB)

template <int NCH>
__device__ inline void blockReduceAtomic(float (&v)[NCH], float* __restrict__ dst) {
    __shared__ float red[4][NCH];  // blockDim.x == 256 -> 4 waves
    const int lane = threadIdx.x & 63;
    const int wv = threadIdx.x >> 6;
#pragma unroll
    for (int c = 0; c < NCH; c++) {
        float x = v[c];
#pragma unroll
        for (int off = 32; off > 0; off >>= 1) x += __shfl_xor(x, off, 64);
        if (lane == 0) red[wv][c] = x;
    }
    __syncthreads();
    for (int c = threadIdx.x; c < NCH; c += 256)
        atomicAdd(dst + c, red[0][c] + red[1][c] + red[2][c] + red[3][c]);
}

// ---------------- Kernel 1: moment accumulation for bn1/bn3 (enc) + bn_sc (feats)
__global__ __launch_bounds__(256) void k_stats1(
    const float* __restrict__ coords, const float* __restrict__ feats,
    const int* __restrict__ idx, float* __restrict__ ws) {
    const int tid = threadIdx.x;
    const int p = blockIdx.x * 256 + tid;
    const int b = p >> 16;
    const int n = p & (NN - 1);

    // --- shortcut feature moments first (retire registers before nbr loop) ---
    {
        float accf[44];
        float f[8];
#pragma unroll
        for (int i = 0; i < 8; i++) f[i] = feats[(b * 8 + i) * NN + n];
#pragma unroll
        for (int i = 0; i < 8; i++) accf[i] = f[i];
        int t2 = 8;
#pragma unroll
        for (int i = 0; i < 8; i++)
#pragma unroll
            for (int j = i; j < 8; j++) accf[t2++] = f[i] * f[j];
        blockReduceAtomic<44>(accf, ws + WS_SC_M);
    }

    // --- enc moments ---
    const float cx = coords[3 * p], cy = coords[3 * p + 1], cz = coords[3 * p + 2];
    const float* cb = coords + b * NN * 3;
    const int4* ip = (const int4*)idx + p * 4;
    float sn0 = 0.f, sn1 = 0.f, sn2 = 0.f;
    float m00 = 0.f, m01 = 0.f, m02 = 0.f, m11 = 0.f, m12 = 0.f, m22 = 0.f;
#pragma unroll
    for (int q = 0; q < 4; q++) {
        int4 v = ip[q];
        int jj[4] = {v.x, v.y, v.z, v.w};
#pragma unroll
        for (int e = 0; e < 4; e++) {
            const int j = jj[e];
            const float nx = cb[3 * j], ny = cb[3 * j + 1], nz = cb[3 * j + 2];
            sn0 += nx; sn1 += ny; sn2 += nz;
            m00 += nx * nx; m01 += nx * ny; m02 += nx * nz;
            m11 += ny * ny; m12 += ny * nz; m22 += nz * nz;
        }
    }
    float acc[27];
    acc[0] = 16.f * cx; acc[1] = 16.f * cy; acc[2] = 16.f * cz;
    acc[3] = sn0; acc[4] = sn1; acc[5] = sn2;
    acc[6] = 16.f * cx * cx; acc[7] = 16.f * cx * cy; acc[8] = 16.f * cx * cz;
    acc[9] = 16.f * cy * cy; acc[10] = 16.f * cy * cz; acc[11] = 16.f * cz * cz;
    acc[12] = cx * sn0; acc[13] = cx * sn1; acc[14] = cx * sn2;
    acc[15] = cy * sn0; acc[16] = cy * sn1; acc[17] = cy * sn2;
    acc[18] = cz * sn0; acc[19] = cz * sn1; acc[20] = cz * sn2;
    acc[21] = m00; acc[22] = m01; acc[23] = m02;
    acc[24] = m11; acc[25] = m12; acc[26] = m22;
    blockReduceAtomic<27>(acc, ws + WS_ENC_M);
}

// ---------------- finalize bn1/bn3 (count NP*NK) and bn_sc (count NP) from moments
__global__ void k_fin1(
    const float* __restrict__ lse1_w, const float* __restrict__ lse1_b,
    const float* __restrict__ g1, const float* __restrict__ bt1,
    const float* __restrict__ lse2_w, const float* __restrict__ lse2_b,
    const float* __restrict__ g3, const float* __restrict__ bt3,
    const float* __restrict__ sc_w, const float* __restrict__ sc_b,
    const float* __restrict__ gsc, const float* __restrict__ btsc,
    float* __restrict__ ws) {
    const int t = threadIdx.x;
    if (t < 16) {
        const int c = t & 7;
        const float* w = (t < 8 ? lse1_w : lse2_w) + c * 10;
        const float bb = (t < 8 ? lse1_b : lse2_b)[c];
        float u[6];
        u[0] = w[0] + w[6]; u[1] = w[1] + w[7]; u[2] = w[2] + w[8];
        u[3] = w[3] - w[6]; u[4] = w[4] - w[7]; u[5] = w[5] - w[8];
        const float beta = bb + w[9];
        const float* M = ws + WS_ENC_M;
        float lin = 0.f;
#pragma unroll
        for (int i = 0; i < 6; i++) lin += u[i] * M[i];
        float quad = u[0] * u[0] * M[6] + 2.f * u[0] * u[1] * M[7] + 2.f * u[0] * u[2] * M[8]
                   + u[1] * u[1] * M[9] + 2.f * u[1] * u[2] * M[10] + u[2] * u[2] * M[11];
#pragma unroll
        for (int i = 0; i < 3; i++)
#pragma unroll
            for (int j = 0; j < 3; j++) quad += 2.f * u[i] * u[3 + j] * M[12 + i * 3 + j];
        quad += u[3] * u[3] * M[21] + 2.f * u[3] * u[4] * M[22] + 2.f * u[3] * u[5] * M[23]
              + u[4] * u[4] * M[24] + 2.f * u[4] * u[5] * M[25] + u[5] * u[5] * M[26];
        const float cnt = (float)NP * (float)NK;
        const float sum = lin + cnt * beta;
        const float ss = quad + 2.f * beta * lin + cnt * beta * beta;
        const float m = sum / cnt, v = ss / cnt - m * m;
        const float g = (t < 8 ? g1 : g3)[c], bt = (t < 8 ? bt1 : bt3)[c];
        const float sc = g * rsqrtf(v + BN_EPS);
        if (t < 8) { ws[WS_BN1_SC + c] = sc; ws[WS_BN1_SH + c] = bt - m * sc; }
        else       { ws[WS_BN3_SC + c] = sc; ws[WS_BN3_SH + c] = bt - m * sc; }
    } else if (t < 48) {
        const int c = t - 16;
        const float* w = sc_w + c * 8;
        const float* S = ws + WS_SC_M;
        float lin = 0.f;
#pragma unroll
        for (int i = 0; i < 8; i++) lin += w[i] * S[i];
        float quad = 0.f;
        int t2 = 0;
#pragma unroll
        for (int i = 0; i < 8; i++)
#pragma unroll
            for (int j = i; j < 8; j++) {
                const float mm = S[8 + t2++];
                quad += (i == j ? 1.f : 2.f) * w[i] * w[j] * mm;
            }
        const float cnt = (float)NP;
        const float bb = sc_b[c];
        const float sum = lin + cnt * bb;
        const float ss = quad + 2.f * bb * lin + cnt * bb * bb;
        const float m = sum / cnt, v = ss / cnt - m * m;
        const float sc = gsc[c] * rsqrtf(v + BN_EPS);
        ws[WS_BNSC_SC + c] = sc; ws[WS_BNSC_SH + c] = btsc[c] - m * sc;
    }
}

// ---------------- Kernel 3: mlp1 + lse1 + pool1 -> y2 (pre-BN), bn_p1 stats
__global__ __launch_bounds__(256) void k_pool1(
    const float* __restrict__ coords, const float* __restrict__ feats,
    const int* __restrict__ idx,
    const float* __restrict__ w1, const float* __restrict__ b1,
    const float* __restrict__ lse1_w, const float* __restrict__ lse1_b,
    const float* __restrict__ p1_sw, const float* __restrict__ p1_w,
    const float* __restrict__ p1_b, float* __restrict__ ws) {
    __shared__ float lws[80], lbs[8], w1s[64], b1s[8], bnsc[8], bnsh[8],
        sws[64], pws[128], pbs[8];
    const int tid = threadIdx.x;
    for (int i = tid; i < 80; i += 256) lws[i] = lse1_w[i];
    if (tid < 8) {
        lbs[tid] = lse1_b[tid]; b1s[tid] = b1[tid]; pbs[tid] = p1_b[tid];
        bnsc[tid] = ws[WS_BN1_SC + tid]; bnsh[tid] = ws[WS_BN1_SH + tid];
    }
    if (tid < 64) {
        w1s[tid] = w1[tid];
        int o = tid >> 3, i2 = tid & 7;
        sws[tid] = p1_sw[o * 16 + i2];  // only rows o<8, cols i<8 matter
    }
    if (tid < 128) pws[tid] = p1_w[tid];
    __syncthreads();

    float st[16] = {};
    const int p = blockIdx.x * 256 + tid;
    if (p < NP) {
        const int b = p >> 16;
        const int n = p & (NN - 1);
        float f[8];
#pragma unroll
        for (int i = 0; i < 8; i++) f[i] = feats[(b * 8 + i) * NN + n];
        float x1[8];
#pragma unroll
        for (int j = 0; j < 8; j++) {
            float y = b1s[j];
#pragma unroll
            for (int i = 0; i < 8; i++) y += f[i] * w1s[j * 8 + i];
            x1[j] = y > 0.f ? y : 0.2f * y;  // LeakyReLU(0.2)
        }
        const float cx = coords[3 * p], cy = coords[3 * p + 1], cz = coords[3 * p + 2];
        const float* cb = coords + b * NN * 3;
        const int4* ip = (const int4*)idx + p * 4;
        int nb[16];
#pragma unroll
        for (int q = 0; q < 4; q++) {
            int4 v = ip[q];
            nb[4 * q] = v.x; nb[4 * q + 1] = v.y; nb[4 * q + 2] = v.z; nb[4 * q + 3] = v.w;
        }
        float l[8] = {}, ac[8] = {};
#pragma unroll
        for (int k = 0; k < 16; k++) {
            const int j = nb[k];
            const float nx = cb[3 * j], ny = cb[3 * j + 1], nz = cb[3 * j + 2];
            const float e6 = cx - nx, e7 = cy - ny, e8 = cz - nz;
            float h[8];
#pragma unroll
            for (int c = 0; c < 8; c++) {
                const float* w = &lws[c * 10];
                float y = lbs[c] + w[9] + cx * w[0] + cy * w[1] + cz * w[2] +
                          nx * w[3] + ny * w[4] + nz * w[5] + e6 * w[6] + e7 * w[7] + e8 * w[8];
                y = y * bnsc[c] + bnsh[c];
                h[c] = y > 0.f ? y : 0.f;
            }
#pragma unroll
            for (int o = 0; o < 8; o++) {
                float s = 0.f;
#pragma unroll
                for (int i = 0; i < 8; i++) s += h[i] * sws[o * 8 + i];
                // k-constant part of score cancels in softmax; |s| small -> no max needed
                float e = __expf(s);
                l[o] += e; ac[o] += e * h[o];
            }
        }
        float agg[16];
#pragma unroll
        for (int o = 0; o < 8; o++) agg[o] = ac[o] / l[o];
#pragma unroll
        for (int o = 0; o < 8; o++) agg[8 + o] = x1[o];  // softmax sums to 1
#pragma unroll
        for (int c = 0; c < 8; c++) {
            float y = pbs[c];
#pragma unroll
            for (int o = 0; o < 16; o++) y += agg[o] * pws[c * 16 + o];
            ws[WS_Y2 + c * NP + p] = y;
            st[c] = y; st[8 + c] = y * y;
        }
    }
    blockReduceAtomic<16>(st, ws + WS_S_Y2);
}

// ---------------- finalize bn_p1 (count NP)
__global__ void k_fin2(const float* __restrict__ g, const float* __restrict__ bt,
                       float* __restrict__ ws) {
    const int t = threadIdx.x;
    if (t < 8) {
        const float cP = 1.f / (float)NP;
        float m = ws[WS_S_Y2 + t] * cP, v = ws[WS_SS_Y2 + t] * cP - m * m;
        float sc = g[t] * rsqrtf(v + BN_EPS);
        ws[WS_BNP1_SC + t] = sc; ws[WS_BNP1_SH + t] = bt[t] - m * sc;
    }
}

// ---------------- Kernel 5: bn_p1+relu -> x2, lse2 + pool2 -> y4 (pre-BN), bn_p2 stats
__global__ __launch_bounds__(256) void k_pool2(
    const float* __restrict__ coords, const int* __restrict__ idx,
    const float* __restrict__ lse2_w, const float* __restrict__ lse2_b,
    const float* __restrict__ p2_sw, const float* __restrict__ p2_w,
    const float* __restrict__ p2_b, float* __restrict__ ws) {
    __shared__ float lws[80], lbs[8], bnsc[8], bnsh[8], p1sc[8], p1sh[8],
        sws[64], pws[256], pbs[16];
    const int tid = threadIdx.x;
    for (int i = tid; i < 80; i += 256) lws[i] = lse2_w[i];
    if (tid < 8) {
        lbs[tid] = lse2_b[tid];
        bnsc[tid] = ws[WS_BN3_SC + tid]; bnsh[tid] = ws[WS_BN3_SH + tid];
        p1sc[tid] = ws[WS_BNP1_SC + tid]; p1sh[tid] = ws[WS_BNP1_SH + tid];
    }
    if (tid < 64) {
        int o = tid >> 3, i2 = tid & 7;
        sws[tid] = p2_sw[o * 16 + i2];
    }
    if (tid < 256) pws[tid] = p2_w[tid];
    if (tid < 16) pbs[tid] = p2_b[tid];
    __syncthreads();

    float st[32] = {};
    const int p = blockIdx.x * 256 + tid;
    if (p < NP) {
        const int b = p >> 16;
        float x2[8];
#pragma unroll
        for (int c = 0; c < 8; c++) {
            float y = ws[WS_Y2 + c * NP + p] * p1sc[c] + p1sh[c];
            x2[c] = y > 0.f ? y : 0.f;
        }
        const float cx = coords[3 * p], cy = coords[3 * p + 1], cz = coords[3 * p + 2];
        const float* cb = coords + b * NN * 3;
        const int4* ip = (const int4*)idx + p * 4;
        int nb[16];
#pragma unroll
        for (int q = 0; q < 4; q++) {
            int4 v = ip[q];
            nb[4 * q] = v.x; nb[4 * q + 1] = v.y; nb[4 * q + 2] = v.z; nb[4 * q + 3] = v.w;
        }
        float l[8] = {}, ac[8] = {};
#pragma unroll
        for (int k = 0; k < 16; k++) {
            const int j = nb[k];
            const float nx = cb[3 * j], ny = cb[3 * j + 1], nz = cb[3 * j + 2];
            const float e6 = cx - nx, e7 = cy - ny, e8 = cz - nz;
            float h[8];
#pragma unroll
            for (int c = 0; c < 8; c++) {
                const float* w = &lws[c * 10];
                float y = lbs[c] + w[9] + cx * w[0] + cy * w[1] + cz * w[2] +
                          nx * w[3] + ny * w[4] + nz * w[5] + e6 * w[6] + e7 * w[7] + e8 * w[8];
                y = y * bnsc[c] + bnsh[c];
                h[c] = y > 0.f ? y : 0.f;
            }
#pragma unroll
            for (int o = 0; o < 8; o++) {
                float s = 0.f;
#pragma unroll
                for (int i = 0; i < 8; i++) s += h[i] * sws[o * 8 + i];
                float e = __expf(s);
                l[o] += e; ac[o] += e * h[o];
            }
        }
        float agg[16];
#pragma unroll
        for (int o = 0; o < 8; o++) agg[o] = ac[o] / l[o];
#pragma unroll
        for (int o = 0; o < 8; o++) agg[8 + o] = x2[o];
#pragma unroll
        for (int c = 0; c < 16; c++) {
            float y = pbs[c];
#pragma unroll
            for (int o = 0; o < 16; o++) y += agg[o] * pws[c * 16 + o];
            ws[WS_Y4 + c * NP + p] = y;
            st[c] = y; st[16 + c] = y * y;
        }
    }
    blockReduceAtomic<32>(st, ws + WS_S_Y4);
}

// ---------------- finalize bn_p2 (count NP)
__global__ void k_fin3(const float* __restrict__ g, const float* __restrict__ bt,
                       float* __restrict__ ws) {
    const int t = threadIdx.x;
    if (t < 16) {
        const float cP = 1.f / (float)NP;
        float m = ws[WS_S_Y4 + t] * cP, v = ws[WS_SS_Y4 + t] * cP - m * m;
        float sc = g[t] * rsqrtf(v + BN_EPS);
        ws[WS_BNP2_SC + t] = sc; ws[WS_BNP2_SH + t] = bt[t] - m * sc;
    }
}

// ---------------- Kernel 7: x4 = relu(bn(y4)); out = leaky(w2@x4 + b2 + bn(sc_w@feats))
__global__ __launch_bounds__(256) void k_final(
    const float* __restrict__ feats, const float* __restrict__ w2,
    const float* __restrict__ b2, const float* __restrict__ sc_w,
    const float* __restrict__ sc_b, const float* __restrict__ ws,
    float* __restrict__ out) {
    __shared__ float w2s[512], b2s[32], scws[256], scbs[32],
        p2sc[16], p2sh[16], scsc[32], scsh[32];
    const int tid = threadIdx.x;
    for (int i = tid; i < 512; i += 256) w2s[i] = w2[i];
    if (tid < 256) scws[tid] = sc_w[tid];
    if (tid < 32) {
        b2s[tid] = b2[tid]; scbs[tid] = sc_b[tid];
        scsc[tid] = ws[WS_BNSC_SC + tid]; scsh[tid] = ws[WS_BNSC_SH + tid];
    }
    if (tid < 16) { p2sc[tid] = ws[WS_BNP2_SC + tid]; p2sh[tid] = ws[WS_BNP2_SH + tid]; }
    __syncthreads();

    const int p = blockIdx.x * 256 + tid;
    if (p >= NP) return;
    const int b = p >> 16;
    const int n = p & (NN - 1);
    float x4[16];
#pragma unroll
    for (int c = 0; c < 16; c++) {
        float y = ws[WS_Y4 + c * NP + p] * p2sc[c] + p2sh[c];
        x4[c] = y > 0.f ? y : 0.f;
    }
    float f[8];
#pragma unroll
    for (int i = 0; i < 8; i++) f[i] = feats[(b * 8 + i) * NN + n];
#pragma unroll
    for (int c = 0; c < 32; c++) {
        float s = scbs[c];
#pragma unroll
        for (int i = 0; i < 8; i++) s += f[i] * scws[c * 8 + i];
        s = s * scsc[c] + scsh[c];  // bn, no activation
        float m = b2s[c];
#pragma unroll
        for (int o = 0; o < 16; o++) m += x4[o] * w2s[c * 16 + o];
        float v = m + s;
        out[(b * 32 + c) * NN + n] = v > 0.f ? v : 0.01f * v;  // LeakyReLU(0.01)
    }
}

extern "C" void kernel_launch(void* const* d_in, const int* in_sizes, int n_in,
                              void* d_out, int out_size, void* d_ws, size_t ws_size,
                              hipStream_t stream) {
    (void)in_sizes; (void)n_in; (void)out_size; (void)ws_size;
    const float* coords = (const float*)d_in[0];
    const float* features = (const float*)d_in[1];
    const int* idx = (const int*)d_in[2];
    const float* w1 = (const float*)d_in[3];
    const float* b1 = (const float*)d_in[4];
    const float* lse1_w = (const float*)d_in[5];
    const float* lse1_b = (const float*)d_in[6];
    const float* lse1_g = (const float*)d_in[7];
    const float* lse1_bt = (const float*)d_in[8];
    const float* p1_sw = (const float*)d_in[9];
    const float* p1_w = (const float*)d_in[10];
    const float* p1_b = (const float*)d_in[11];
    const float* p1_g = (const float*)d_in[12];
    const float* p1_bt = (const float*)d_in[13];
    const float* lse2_w = (const float*)d_in[14];
    const float* lse2_b = (const float*)d_in[15];
    const float* lse2_g = (const float*)d_in[16];
    const float* lse2_bt = (const float*)d_in[17];
    const float* p2_sw = (const float*)d_in[18];
    const float* p2_w = (const float*)d_in[19];
    const float* p2_b = (const float*)d_in[20];
    const float* p2_g = (const float*)d_in[21];
    const float* p2_bt = (const float*)d_in[22];
    const float* w2 = (const float*)d_in[23];
    const float* b2 = (const float*)d_in[24];
    const float* sc_w = (const float*)d_in[25];
    const float* sc_b = (const float*)d_in[26];
    const float* sc_g = (const float*)d_in[27];
    const float* sc_bt = (const float*)d_in[28];
    float* ws = (float*)d_ws;
    float* out = (float*)d_out;

    hipMemsetAsync(ws, 0, 144 * sizeof(float), stream);
    k_stats1<<<NP / 256, 256, 0, stream>>>(coords, features, idx, ws);
    k_fin1<<<1, 64, 0, stream>>>(lse1_w, lse1_b, lse1_g, lse1_bt,
                                 lse2_w, lse2_b, lse2_g, lse2_bt,
                                 sc_w, sc_b, sc_g, sc_bt, ws);
    k_pool1<<<NP / 256, 256, 0, stream>>>(coords, features, idx, w1, b1, lse1_w,
                                          lse1_b, p1_sw, p1_w, p1_b, ws);
    k_fin2<<<1, 64, 0, stream>>>(p1_g, p1_bt, ws);
    k_pool2<<<NP / 256, 256, 0, stream>>>(coords, idx, lse2_w, lse2_b, p2_sw,
                                          p2_w, p2_b, ws);
    k_fin3<<<1, 64, 0, stream>>>(p2_g, p2_bt, ws);
    k_final<<<NP / 256, 256, 0, stream>>>(features, w2, b2, sc_w, sc_b, ws, out);
}